// Round 1
// baseline (184.097 us; speedup 1.0000x reference)
//
#include <hip/hip_runtime.h>

// TorchNeighborList, N=4096, cutoff=5, no PBC.
// Output layout (all float32 values, concatenated flat, P = N(N-1)/2):
//   [0      , 2P )  idx_i   (sentinel 4096 in padding)
//   [2P     , 4P )  idx_j   (sentinel 4096 in padding)
//   [4P     , 10P)  Rij     [2P,3] = pos[partner]-pos[self]; 0 in padding
//   [10P    , 16P)  cell_offset (all zero)
//   [16P    , 18P)  mask    (1.0 valid, 0.0 padding)
//   [18P]           num_pairs
// Ordering (stable argsort by source idx of concat(triu_i, triu_j)):
//   for each atom a: partners j>a ascending, then partners i<a ascending.

#define NA 4096
static constexpr long long PP = (long long)NA * (NA - 1) / 2;  // 8,386,560
static constexpr long long TP = 2 * PP;                        // 16,773,120

// Canonical IEEE f32 distance^2, no fma contraction, left-to-right sum —
// must bit-match the host f32 reference so the cutoff test agrees.
__device__ __forceinline__ float dist2_exact(float dx, float dy, float dz) {
    return __fadd_rn(__fadd_rn(__fmul_rn(dx, dx), __fmul_rn(dy, dy)),
                     __fmul_rn(dz, dz));
}

// ---- K1: fill whole output with padding pattern (float4 stores) ----------
__global__ void fill_kernel(float4* __restrict__ out4, long long n4, long long idx4) {
    long long stride = (long long)gridDim.x * blockDim.x;
    for (long long i = (long long)blockIdx.x * blockDim.x + threadIdx.x; i < n4; i += stride) {
        float v = (i < idx4) ? 4096.0f : 0.0f;   // idx regions get sentinel N
        out4[i] = make_float4(v, v, v, v);
    }
}

// ---- K2: per-atom neighbor count (1 wave per atom) -----------------------
__global__ void count_kernel(const float* __restrict__ pos, int* __restrict__ cnt) {
    int wave = (int)(((long long)blockIdx.x * blockDim.x + threadIdx.x) >> 6);
    int lane = threadIdx.x & 63;
    if (wave >= NA) return;
    float ax = pos[3 * wave + 0], ay = pos[3 * wave + 1], az = pos[3 * wave + 2];
    int c = 0;
    for (int base = 0; base < NA; base += 64) {
        int p = base + lane;
        float dx = pos[3 * p + 0] - ax;
        float dy = pos[3 * p + 1] - ay;
        float dz = pos[3 * p + 2] - az;
        float d2 = dist2_exact(dx, dy, dz);
        if (p != wave && __fsqrt_rn(d2) < 5.0f) c++;
    }
    for (int off = 32; off; off >>= 1) c += __shfl_down(c, off, 64);
    if (lane == 0) cnt[wave] = c;
}

// ---- K3: exclusive scan of 4096 counts (single block) --------------------
__global__ void scan_kernel(const int* __restrict__ cnt, int* __restrict__ off,
                            float* __restrict__ out_np) {
    __shared__ int sdata[1024];
    int tid = threadIdx.x;
    int v[4];
    int s = 0;
    for (int k = 0; k < 4; k++) { v[k] = cnt[tid * 4 + k]; s += v[k]; }
    sdata[tid] = s;
    __syncthreads();
    for (int d = 1; d < 1024; d <<= 1) {
        int t = (tid >= d) ? sdata[tid - d] : 0;
        __syncthreads();
        sdata[tid] += t;
        __syncthreads();
    }
    int excl = (tid == 0) ? 0 : sdata[tid - 1];
    for (int k = 0; k < 4; k++) { off[tid * 4 + k] = excl; excl += v[k]; }
    if (tid == 1023) out_np[0] = (float)sdata[1023];   // num_pairs
}

// ---- K4: rank-ordered scatter of valid rows (1 wave per atom) ------------
__global__ void scatter_kernel(const float* __restrict__ pos, const int* __restrict__ off,
                               float* __restrict__ out) {
    int wave = (int)(((long long)blockIdx.x * blockDim.x + threadIdx.x) >> 6);
    int lane = threadIdx.x & 63;
    if (wave >= NA) return;
    int a = wave;
    float ax = pos[3 * a + 0], ay = pos[3 * a + 1], az = pos[3 * a + 2];
    int o = off[a];
    // phase 0: partners > a (ascending); phase 1: partners < a (ascending)
    for (int phase = 0; phase < 2; ++phase) {
        int lo = (phase == 0) ? a + 1 : 0;
        int hi = (phase == 0) ? NA : a;
        for (int base = lo & ~63; base < hi; base += 64) {
            int p = base + lane;
            bool valid = (p >= lo) && (p < hi);
            float px = 0.f, py = 0.f, pz = 0.f;
            if (valid) {
                px = pos[3 * p + 0]; py = pos[3 * p + 1]; pz = pos[3 * p + 2];
                float d2 = dist2_exact(px - ax, py - ay, pz - az);
                valid = __fsqrt_rn(d2) < 5.0f;
            }
            unsigned long long m = __ballot(valid);
            if (valid) {
                int idx = o + __popcll(m & ((1ull << lane) - 1ull));
                out[idx] = (float)a;                       // idx_i
                out[TP + idx] = (float)p;                  // idx_j
                long long r = 2 * TP + 3LL * idx;          // Rij row
                out[r + 0] = px - ax;                      // pos[partner]-pos[self]
                out[r + 1] = py - ay;
                out[r + 2] = pz - az;
                out[8 * TP + idx] = 1.0f;                  // mask
            }
            o += __popcll(m);
        }
    }
}

extern "C" void kernel_launch(void* const* d_in, const int* in_sizes, int n_in,
                              void* d_out, int out_size, void* d_ws, size_t ws_size,
                              hipStream_t stream) {
    const float* pos = (const float*)d_in[0];   // [4096,3] f32
    float* out = (float*)d_out;
    int* cnt = (int*)d_ws;
    int* off = cnt + NA;

    const long long n4 = (18 * PP) / 4;   // 37,739,520 float4s cover [0, 18P)
    const long long idx4 = PP;            // first 4P floats = P float4s (idx regions)

    // count/scan first (independent of fill), then fill, then scatter
    count_kernel<<<NA / 4, 256, 0, stream>>>(pos, cnt);
    scan_kernel<<<1, 1024, 0, stream>>>(cnt, off, out + 18 * PP);
    fill_kernel<<<2048, 256, 0, stream>>>((float4*)out, n4, idx4);
    scatter_kernel<<<NA / 4, 256, 0, stream>>>(pos, off, out);
}

// Round 2
// 182.034 us; speedup vs baseline: 1.0113x; 1.0113x over previous
//
#include <hip/hip_runtime.h>

// TorchNeighborList, N=4096, cutoff=5, no PBC.
// Output layout (all float32 values, concatenated flat, P = N(N-1)/2):
//   [0      , 2P )  idx_i   (sentinel 4096 in padding)
//   [2P     , 4P )  idx_j   (sentinel 4096 in padding)
//   [4P     , 10P)  Rij     [2P,3] = pos[partner]-pos[self]; 0 in padding
//   [10P    , 16P)  cell_offset (all zero)
//   [16P    , 18P)  mask    (1.0 valid, 0.0 padding)
//   [18P]           num_pairs
// Ordering (stable argsort by source idx of concat(triu_i, triu_j)):
//   for each atom a: partners j>a ascending, then partners i<a ascending.
// Valid rows are exactly ranks [0, num_pairs) — dense.

#define NA 4096
static constexpr long long PP = (long long)NA * (NA - 1) / 2;  // 8,386,560
static constexpr long long TP = 2 * PP;                        // 16,773,120
static constexpr int FILL_BLOCKS = 2048;
static constexpr int COUNT_BLOCKS = NA / 4;                    // 1024 (4 waves/block)

// Canonical IEEE f32 distance^2, no fma contraction, left-to-right sum —
// must bit-match the host f32 reference so the cutoff test agrees.
__device__ __forceinline__ float dist2_exact(float dx, float dy, float dz) {
    return __fadd_rn(__fadd_rn(__fmul_rn(dx, dx), __fmul_rn(dy, dy)),
                     __fmul_rn(dz, dz));
}

// ---- K1: full-output fill (BW-bound) + per-atom count (hidden under fill) --
__global__ void fill_count_kernel(const float* __restrict__ pos, int* __restrict__ cnt,
                                  float4* __restrict__ out4) {
    int bid = blockIdx.x;
    if (bid < FILL_BLOCKS) {
        const int n4 = (int)(18 * PP / 4);   // 37,739,520 float4s = whole [0,18P)
        const int idx4 = (int)PP;            // first P float4s = idx_i+idx_j region
        const int stride = FILL_BLOCKS * 256;
        const int i0 = bid * 256 + threadIdx.x;
        const float4 sent = make_float4(4096.f, 4096.f, 4096.f, 4096.f);
        const float4 zero = make_float4(0.f, 0.f, 0.f, 0.f);
        // two uniform loops: no per-iteration region select
        for (int i = i0; i < idx4; i += stride) out4[i] = sent;
        for (int i = idx4 + i0; i < n4; i += stride) out4[i] = zero;
    } else {
        // count blocks: one wave per atom
        int cb = bid - FILL_BLOCKS;                  // 0..1023
        int wid = threadIdx.x >> 6, lane = threadIdx.x & 63;
        int a = cb * 4 + wid;                        // 0..4095
        float ax = pos[3 * a + 0], ay = pos[3 * a + 1], az = pos[3 * a + 2];
        int c = 0;
        for (int base = 0; base < NA; base += 64) {
            int p = base + lane;
            float dx = pos[3 * p + 0] - ax;
            float dy = pos[3 * p + 1] - ay;
            float dz = pos[3 * p + 2] - az;
            if (p != a && __fsqrt_rn(dist2_exact(dx, dy, dz)) < 5.0f) c++;
        }
        for (int off = 32; off; off >>= 1) c += __shfl_down(c, off, 64);
        if (lane == 0) cnt[a] = c;
    }
}

// ---- K2: inline exclusive scan + rank-ordered scatter (1 wave per atom) ----
__global__ void scatter_kernel(const float* __restrict__ pos, const int* __restrict__ cnt,
                               float* __restrict__ out) {
    int wid = threadIdx.x >> 6, lane = threadIdx.x & 63;
    int a = blockIdx.x * 4 + wid;                    // 0..4095
    float ax = pos[3 * a + 0], ay = pos[3 * a + 1], az = pos[3 * a + 2];

    // exclusive prefix over cnt[0..a)  (cnt is 16 KB, L2-resident)
    int s = 0;
    for (int i = lane; i < a; i += 64) s += cnt[i];
    for (int off = 32; off; off >>= 1) s += __shfl_down(s, off, 64);
    int o = __shfl(s, 0, 64);                        // broadcast wave sum

    if (a == NA - 1 && lane == 0) out[18 * PP] = (float)(o + cnt[a]);  // num_pairs

    // phase 0: partners > a (ascending); phase 1: partners < a (ascending)
    for (int phase = 0; phase < 2; ++phase) {
        int lo = (phase == 0) ? a + 1 : 0;
        int hi = (phase == 0) ? NA : a;
        for (int base = lo & ~63; base < hi; base += 64) {
            int p = base + lane;
            bool valid = (p >= lo) && (p < hi);
            float px = 0.f, py = 0.f, pz = 0.f;
            if (valid) {
                px = pos[3 * p + 0]; py = pos[3 * p + 1]; pz = pos[3 * p + 2];
                valid = __fsqrt_rn(dist2_exact(px - ax, py - ay, pz - az)) < 5.0f;
            }
            unsigned long long m = __ballot(valid);
            if (valid) {
                int idx = o + __popcll(m & ((1ull << lane) - 1ull));
                out[idx] = (float)a;                       // idx_i
                out[TP + idx] = (float)p;                  // idx_j
                long long r = 2 * TP + 3LL * idx;          // Rij row
                out[r + 0] = px - ax;                      // pos[partner]-pos[self]
                out[r + 1] = py - ay;
                out[r + 2] = pz - az;
                out[8 * TP + idx] = 1.0f;                  // mask
            }
            o += __popcll(m);
        }
    }
}

extern "C" void kernel_launch(void* const* d_in, const int* in_sizes, int n_in,
                              void* d_out, int out_size, void* d_ws, size_t ws_size,
                              hipStream_t stream) {
    const float* pos = (const float*)d_in[0];   // [4096,3] f32
    float* out = (float*)d_out;
    int* cnt = (int*)d_ws;

    fill_count_kernel<<<FILL_BLOCKS + COUNT_BLOCKS, 256, 0, stream>>>(pos, cnt, (float4*)out);
    scatter_kernel<<<COUNT_BLOCKS, 256, 0, stream>>>(pos, cnt, out);
}